// Round 10
// baseline (3251.334 us; speedup 1.0000x reference)
//
#include <hip/hip_runtime.h>
#include <hip/hip_bf16.h>
#include <stdint.h>

// ---------------------------------------------------------------------------
// DeepLSTMDecoderLayer R10 = R7 (best, 3002us) + scan polish only:
//  - part[2][4][16][132] padding (gate-phase reads conflict-free)
//  - gx prefetched one full step ahead (off the spin vmcnt path)
//  - gather re-issued at loop tail after publish; spin = check/reload/sleep
//    (reload RT overlaps sleep)
// R9 lesson: FFN1 worker fusion DEMOTED (worker L3 traffic inflated the
// scan's bypass-load latency; fused 2341us > scan 2035 + ffn1 137).
// ws layout (MiB offsets), peak ~234 MiB:
//   0 xcb(32) | 32 wlp(16) | 48 whp(8) | 56 w1t(8) | 64 w2t(8) | 72 pb(16K)
//   73 hbuf(16.04) | 90 memb(16) | 106 wt[8](16) | 122 bq | 138 bk | 154 bv
//   170 ao_s | 186 ao_t | 202 c32(32)
//   overlays at 90: gx f32 (90..218, after attention) ; ffn1 bf16 (90..154)
// ---------------------------------------------------------------------------

typedef unsigned short u16;
typedef unsigned int u32;
typedef unsigned long long u64;
typedef __bf16 bf16x8 __attribute__((ext_vector_type(8)));
typedef float f32x4 __attribute__((ext_vector_type(4)));
typedef int int32x4 __attribute__((ext_vector_type(4)));
typedef unsigned long long u64x2 __attribute__((ext_vector_type(2)));

#define DEV static __device__ __forceinline__

DEV u16 f2bf(float x) {
  u32 u = __builtin_bit_cast(u32, x);
  u += 0x7FFF + ((u >> 16) & 1);  // round-to-nearest-even
  return (u16)(u >> 16);
}

DEV bf16x8 ldfrag(const void* p) {
  int32x4 v = *(const int32x4*)p;
  return __builtin_bit_cast(bf16x8, v);
}

DEV bf16x8 mkfrag(u64 lo, u64 hi) {
  u64x2 v;
  v.x = lo;
  v.y = hi;
  return __builtin_bit_cast(bf16x8, v);
}

DEV f32x4 mfma_bf16(bf16x8 a, bf16x8 b, f32x4 c) {
  return __builtin_amdgcn_mfma_f32_16x16x32_bf16(a, b, c, 0, 0, 0);
}

DEV u64 aload(const u64* p) {
  return __hip_atomic_load(p, __ATOMIC_RELAXED, __HIP_MEMORY_SCOPE_AGENT);
}

// async global->LDS, 16B per lane; LDS dest is wave-uniform base (+lane*16 HW)
DEV void load_lds16(const u16* g, u16* l) {
  __builtin_amdgcn_global_load_lds(
      (__attribute__((address_space(1))) void*)(uintptr_t)g,
      (__attribute__((address_space(3))) void*)(uintptr_t)l, 16, 0, 0);
}

// ---------------- conversion kernels ----------------

__global__ __launch_bounds__(256) void cvt_bf16_kernel(u16* __restrict__ out,
                                                       const float* __restrict__ in,
                                                       int n4) {
  int i = blockIdx.x * 256 + threadIdx.x;
  if (i >= n4) return;
  float4 v = ((const float4*)in)[i];
  ushort4 s;
  s.x = f2bf(v.x); s.y = f2bf(v.y); s.z = f2bf(v.z); s.w = f2bf(v.w);
  ((ushort4*)out)[i] = s;
}

// x[8192][1024] f32 -> xcb[r][0..1023] with row stride 2048
__global__ __launch_bounds__(256) void cvt_x_kernel(u16* __restrict__ out,
                                                    const float* __restrict__ in) {
  int i = blockIdx.x * 256 + threadIdx.x;
  int r = i >> 8, cg4 = i & 255;
  float4 v = ((const float4*)in)[i];
  ushort4 s;
  s.x = f2bf(v.x); s.y = f2bf(v.y); s.z = f2bf(v.z); s.w = f2bf(v.w);
  *(ushort4*)(out + (size_t)r * 2048 + cg4 * 4) = s;
}

// out[n*K + k] = in[(k+koff)*N + n] * scale
__global__ __launch_bounds__(256) void convt_kernel(u16* __restrict__ out,
                                                    const float* __restrict__ in,
                                                    int K, int N, int koff, float scale) {
  __shared__ float tile[32][33];
  const int tid = threadIdx.x;
  const int n0 = blockIdx.x * 32, k0 = blockIdx.y * 32;
  const int c = tid & 31, r = tid >> 5;
#pragma unroll
  for (int i = 0; i < 4; ++i)
    tile[r + i * 8][c] = in[(size_t)(k0 + r + i * 8 + koff) * N + n0 + c];
  __syncthreads();
#pragma unroll
  for (int i = 0; i < 4; ++i)
    out[(size_t)(n0 + r + i * 8) * K + k0 + c] = f2bf(tile[c][r + i * 8] * scale);
}

// packed LSTM weight: out[(u*4+g)*K + k] = lstm_w[(k+koff)*4096 + g*1024 + u]
__global__ __launch_bounds__(256) void convt_perm_kernel(u16* __restrict__ out,
                                                         const float* __restrict__ in,
                                                         int K, int koff) {
  __shared__ float tile[32][33];
  const int tid = threadIdx.x;
  const int u0 = blockIdx.x * 32, k0 = blockIdx.y * 32, g = blockIdx.z;
  const int c = tid & 31, r = tid >> 5;
#pragma unroll
  for (int i = 0; i < 4; ++i)
    tile[r + i * 8][c] = in[(size_t)(k0 + r + i * 8 + koff) * 4096 + g * 1024 + u0 + c];
  __syncthreads();
#pragma unroll
  for (int i = 0; i < 4; ++i)
    out[(size_t)((u0 + r + i * 8) * 4 + g) * K + k0 + c] = f2bf(tile[c][r + i * 8]);
}

__global__ __launch_bounds__(256) void pack_bias_kernel(float* __restrict__ out,
                                                        const float* __restrict__ in) {
  int p = blockIdx.x * 256 + threadIdx.x;  // 4096
  out[p] = in[(p & 3) * 1024 + (p >> 2)];
}

// ---------------- GEMM: C[M,N] = A[M,K] @ Bt[N,K]^T (+bias, +cacc, relu, perm)
// 128x128 tile, BK=32, global_load_lds staging. grid (N/128, M/128), 256 thr.
// PERM==2: out row r -> (r&15)*512 + (r>>4)
template <int OUTBF, int ACCUM, int RELU, int PERM>
__global__ __launch_bounds__(256) void gemm_bt_kernel(
    const u16* __restrict__ A, int lda, const u16* __restrict__ Bt,
    const float* __restrict__ bias, float bscale,
    void* __restrict__ outp, int ostride,
    const float* __restrict__ cacc, int cstride, int K) {
  __shared__ u16 As[128 * 32];
  __shared__ u16 Bs[128 * 32];
  const int tid = threadIdx.x;
  const int wave = tid >> 6, lane = tid & 63;
  const int lr = lane & 15, lg = lane >> 4;
  const int m0 = blockIdx.y * 128, n0 = blockIdx.x * 128;
  const int wr = (wave >> 1) * 64, wc = (wave & 1) * 64;

  f32x4 acc[4][4] = {};

  const int sr = lane >> 2, sce = (lane & 3) * 8;
  const u16* gA = A + (size_t)(m0 + wave * 16 + sr) * lda + sce;
  const u16* gB = Bt + (size_t)(n0 + wave * 16 + sr) * K + sce;
  u16* lA = As + wave * 16 * 32;
  u16* lB = Bs + wave * 16 * 32;

  for (int k0 = 0; k0 < K; k0 += 32) {
    __syncthreads();
    load_lds16(gA + k0, lA);
    load_lds16(gA + k0 + (size_t)64 * lda, lA + 64 * 32);
    load_lds16(gB + k0, lB);
    load_lds16(gB + k0 + (size_t)64 * K, lB + 64 * 32);
    __syncthreads();
    bf16x8 af[4], bfr[4];
    const u16* pa = As + (wr + lr) * 32 + lg * 8;
    const u16* pb = Bs + (wc + lr) * 32 + lg * 8;
#pragma unroll
    for (int i = 0; i < 4; ++i) af[i] = ldfrag(pa + i * 16 * 32);
#pragma unroll
    for (int j = 0; j < 4; ++j) bfr[j] = ldfrag(pb + j * 16 * 32);
#pragma unroll
    for (int i = 0; i < 4; ++i)
#pragma unroll
      for (int j = 0; j < 4; ++j)
        acc[i][j] = mfma_bf16(af[i], bfr[j], acc[i][j]);
  }

  const int col0 = n0 + wc + lr;
  const int row0 = m0 + wr + lg * 4;
#pragma unroll
  for (int i = 0; i < 4; ++i) {
#pragma unroll
    for (int j = 0; j < 4; ++j) {
      const int c = col0 + j * 16;
      const float bv = bias ? bias[c] * bscale : 0.f;
#pragma unroll
      for (int ii = 0; ii < 4; ++ii) {
        const int r = row0 + i * 16 + ii;
        float v = acc[i][j][ii] + bv;
        if (ACCUM) v += cacc[(size_t)r * cstride + c];
        if (RELU) v = fmaxf(v, 0.f);
        const int rp = (PERM == 2) ? ((r & 15) * 512 + (r >> 4)) : r;
        if (OUTBF) ((u16*)outp)[(size_t)rp * ostride + c] = f2bf(v);
        else       ((float*)outp)[(size_t)rp * ostride + c] = v;
      }
    }
  }
}

// ---------------- flash attention (validated R1/R2) ----------------
template <int CAUSAL>
__global__ __launch_bounds__(256) void flash_kernel(
    const u16* __restrict__ Q, const u16* __restrict__ Kb, const u16* __restrict__ Vb,
    const float* __restrict__ sbias, u16* __restrict__ O) {
  __shared__ u16 Kl[64 * 72];
  __shared__ u16 Vt[64 * 72];
  __shared__ u16 Pl[64 * 72];
  const int tid = threadIdx.x, wave = tid >> 6, lane = tid & 63;
  const int lr = lane & 15, lg = lane >> 4;
  const int q0 = blockIdx.x * 64, hh = blockIdx.y, b = blockIdx.z;

  bf16x8 qf[2];
  {
    const u16* qp = Q + (size_t)(b * 512 + q0 + wave * 16 + lr) * 1024 + hh * 64 + lg * 8;
    qf[0] = ldfrag(qp);
    qf[1] = ldfrag(qp + 32);
  }
  f32x4 oacc[4] = {};
  float mrun[4], lsum[4];
#pragma unroll
  for (int ii = 0; ii < 4; ++ii) { mrun[ii] = -3e38f; lsum[ii] = 0.f; }

  const int ntiles = CAUSAL ? (q0 / 64 + 1) : 8;
  for (int ti = 0; ti < ntiles; ++ti) {
    const int s0 = ti * 64;
    {
      const int r = tid >> 2, ch = (tid & 3) * 16;
      const u16* kp = Kb + (size_t)(b * 512 + s0 + r) * 1024 + hh * 64 + ch;
      const u16* vp = Vb + (size_t)(b * 512 + s0 + r) * 1024 + hh * 64 + ch;
      int32x4 k0v = *(const int32x4*)kp;
      int32x4 k1v = *(const int32x4*)(kp + 8);
      int32x4 v0v = *(const int32x4*)vp;
      int32x4 v1v = *(const int32x4*)(vp + 8);
      *(int32x4*)&Kl[r * 72 + ch] = k0v;
      *(int32x4*)&Kl[r * 72 + ch + 8] = k1v;
      const u16* v0p = (const u16*)&v0v;
      const u16* v1p = (const u16*)&v1v;
#pragma unroll
      for (int j = 0; j < 8; ++j) {
        Vt[(ch + j) * 72 + r] = v0p[j];
        Vt[(ch + 8 + j) * 72 + r] = v1p[j];
      }
    }
    __syncthreads();
    f32x4 sf[4] = {};
#pragma unroll
    for (int j = 0; j < 4; ++j)
#pragma unroll
      for (int ks = 0; ks < 2; ++ks) {
        bf16x8 kf = ldfrag(&Kl[(j * 16 + lr) * 72 + ks * 32 + lg * 8]);
        sf[j] = mfma_bf16(qf[ks], kf, sf[j]);
      }
    if (!CAUSAL) {
#pragma unroll
      for (int j = 0; j < 4; ++j) {
        const float bv = sbias[b * 512 + s0 + j * 16 + lr];
#pragma unroll
        for (int ii = 0; ii < 4; ++ii) sf[j][ii] += bv;
      }
    } else {
#pragma unroll
      for (int j = 0; j < 4; ++j) {
        const int s = s0 + j * 16 + lr;
#pragma unroll
        for (int ii = 0; ii < 4; ++ii) {
          const int q = q0 + wave * 16 + lg * 4 + ii;
          if (s > q) sf[j][ii] -= 1e9f;
        }
      }
    }
    float sc[4], rs[4];
#pragma unroll
    for (int ii = 0; ii < 4; ++ii) {
      float m = fmaxf(fmaxf(sf[0][ii], sf[1][ii]), fmaxf(sf[2][ii], sf[3][ii]));
#pragma unroll
      for (int off = 1; off < 16; off <<= 1) m = fmaxf(m, __shfl_xor(m, off));
      const float mn = fmaxf(mrun[ii], m);
      sc[ii] = __expf(mrun[ii] - mn);
      mrun[ii] = mn;
      rs[ii] = 0.f;
    }
#pragma unroll
    for (int j = 0; j < 4; ++j)
#pragma unroll
      for (int ii = 0; ii < 4; ++ii) {
        const float p = __expf(sf[j][ii] - mrun[ii]);
        rs[ii] += p;
        Pl[(wave * 16 + lg * 4 + ii) * 72 + j * 16 + lr] = f2bf(p);
      }
#pragma unroll
    for (int ii = 0; ii < 4; ++ii) {
      float r = rs[ii];
#pragma unroll
      for (int off = 1; off < 16; off <<= 1) r += __shfl_xor(r, off);
      lsum[ii] = lsum[ii] * sc[ii] + r;
    }
#pragma unroll
    for (int df = 0; df < 4; ++df)
#pragma unroll
      for (int ii = 0; ii < 4; ++ii) oacc[df][ii] *= sc[ii];
    __syncthreads();
    bf16x8 pf[2];
    pf[0] = ldfrag(&Pl[(wave * 16 + lr) * 72 + lg * 8]);
    pf[1] = ldfrag(&Pl[(wave * 16 + lr) * 72 + 32 + lg * 8]);
#pragma unroll
    for (int df = 0; df < 4; ++df)
#pragma unroll
      for (int ks = 0; ks < 2; ++ks) {
        bf16x8 vf = ldfrag(&Vt[(df * 16 + lr) * 72 + ks * 32 + lg * 8]);
        oacc[df] = mfma_bf16(pf[ks], vf, oacc[df]);
      }
    __syncthreads();
  }
#pragma unroll
  for (int df = 0; df < 4; ++df)
#pragma unroll
    for (int ii = 0; ii < 4; ++ii) {
      const float v = oacc[df][ii] / lsum[ii];
      O[(size_t)(b * 512 + q0 + wave * 16 + lg * 4 + ii) * 1024 + hh * 64 + df * 16 + lr] =
          f2bf(v);
    }
}

// ---------------- persistent LSTM scan R10 (R7 + polish) ----------------
// 32 WGs x 256 thr (1/CU). WG g owns units [g*32,+32) = packed cols [g*128,+128).
// Split-K: wave w computes ALL 128 pcols over K in [w*256,+256); gathers its
// own 8KB of h(t) direct to regs, spinning on sentinel (0xFF..F = 4x bf16
// NaN; each u64 written by one store -> atomically sentinel-or-valid).
// Partials -> parity LDS (PADDED 132); ONE barrier/step. Publish: plain
// agent stores, no drain. Gather re-issued at loop tail; gx one step ahead.
#define SCAN_NW 32
__global__ __launch_bounds__(256, 1) void lstm_scan_kernel(
    const u16* __restrict__ Whp, const float* __restrict__ gx,
    u16* __restrict__ hbuf) {
  const int tid = threadIdx.x, wave = tid >> 6, lane = tid & 63;
  const int lr = lane & 15, lg = lane >> 4;
  const int g = blockIdx.x;
  __shared__ float part[2][4][16][132];  // padded: gate reads conflict-free
  const int gb = tid >> 4;               // gate-phase batch row 0..15
  const int up = tid & 15;               // gate-phase unit pair: 2up, 2up+1
  float cs0 = 0.f, cs1 = 0.f;
  const u64 SENT = 0xFFFFFFFFFFFFFFFFull;

  const u16* wbase = Whp + (size_t)(g * 128 + lr) * 1024 + wave * 256 + lg * 8;
  const float* gxp = gx + (size_t)gb * 512 * 4096 + g * 128 + up * 8;
  const size_t goff = (size_t)lr * 1024 + wave * 256 + lg * 8;

  u64 hw[16];
#define ISSUE(t)                                                               \
  {                                                                            \
    const u16* hp_ = hbuf + (size_t)(t) * 16384 + goff;                        \
    _Pragma("unroll") for (int kc = 0; kc < 8; ++kc) {                         \
      hw[kc * 2] = aload((const u64*)(hp_ + kc * 32));                         \
      hw[kc * 2 + 1] = aload((const u64*)(hp_ + kc * 32 + 4));                 \
    }                                                                          \
  }

  ISSUE(0);
  float4 gxv0 = *(const float4*)gxp;
  float4 gxv1 = *(const float4*)(gxp + 4);
  for (int t = 0; t < 512; ++t) {
    // NEXT step's gx issued now: full step of latency hiding, and the spin's
    // implicit vmcnt wait never blocks on a fresh HBM load
    float4 gxn0, gxn1;
    if (t + 1 < 512) {
      gxn0 = *(const float4*)(gxp + (size_t)(t + 1) * 4096);
      gxn1 = *(const float4*)(gxp + (size_t)(t + 1) * 4096 + 4);
    }
    // spin: check -> masked reload -> sleep (reload RT overlaps the sleep)
    {
      const u16* hp_ = hbuf + (size_t)t * 16384 + goff;
      int guard = 0;
      for (;;) {
        bool ok = true;
#pragma unroll
        for (int i = 0; i < 16; ++i) ok &= (hw[i] != SENT);
        if (__all((int)ok)) break;
#pragma unroll
        for (int kc = 0; kc < 8; ++kc) {
          if (hw[kc * 2] == SENT)
            hw[kc * 2] = aload((const u64*)(hp_ + kc * 32));
          if (hw[kc * 2 + 1] == SENT)
            hw[kc * 2 + 1] = aload((const u64*)(hp_ + kc * 32 + 4));
        }
        __builtin_amdgcn_s_sleep(2);
        if (++guard > (1 << 20)) break;  // insurance against hang
      }
    }
    // partial GEMM: this wave's K-quarter, all 128 pcols, 16 batches
    f32x4 acc[8] = {};
#pragma unroll
    for (int kc = 0; kc < 8; ++kc) {
      const bf16x8 hf = mkfrag(hw[kc * 2], hw[kc * 2 + 1]);
#pragma unroll
      for (int j = 0; j < 8; ++j)
        acc[j] = mfma_bf16(hf, ldfrag(wbase + j * 16 * 1024 + kc * 32), acc[j]);
    }
    const int p = t & 1;
#pragma unroll
    for (int j = 0; j < 8; ++j)
#pragma unroll
      for (int ii = 0; ii < 4; ++ii)
        part[p][wave][lg * 4 + ii][j * 16 + lr] = acc[j][ii];
    __syncthreads();  // the ONLY barrier per step (parity protects overlap)
    // gate phase: thread (gb, up) -> local units 2up, 2up+1
    float4 sA = *(const float4*)&part[p][0][gb][up * 8];
    float4 sB = *(const float4*)&part[p][0][gb][up * 8 + 4];
#pragma unroll
    for (int w = 1; w < 4; ++w) {
      const float4 a = *(const float4*)&part[p][w][gb][up * 8];
      const float4 b = *(const float4*)&part[p][w][gb][up * 8 + 4];
      sA.x += a.x; sA.y += a.y; sA.z += a.z; sA.w += a.w;
      sB.x += b.x; sB.y += b.y; sB.z += b.z; sB.w += b.w;
    }
    float hA, hB;
    {
      const float si = sA.x + gxv0.x, sj = sA.y + gxv0.y;
      const float sf_ = sA.z + gxv0.z, so = sA.w + gxv0.w;
      const float ig = 1.f / (1.f + __expf(-si));
      const float jg = 1.f - 2.f / (__expf(2.f * sj) + 1.f);
      const float fg = 1.f / (1.f + __expf(-sf_));
      const float og = 1.f / (1.f + __expf(-so));
      cs0 = fg * cs0 + ig * jg;
      hA = og * (1.f - 2.f / (__expf(2.f * cs0) + 1.f));
    }
    {
      const float si = sB.x + gxv1.x, sj = sB.y + gxv1.y;
      const float sf_ = sB.z + gxv1.z, so = sB.w + gxv1.w;
      const float ig = 1.f / (1.f + __expf(-si));
      const float jg = 1.f - 2.f / (__expf(2.f * sj) + 1.f);
      const float fg = 1.f / (1.f + __expf(-sf_));
      const float og = 1.f / (1.f + __expf(-so));
      cs1 = fg * cs1 + ig * jg;
      hB = og * (1.f - 2.f / (__expf(2.f * cs1) + 1.f));
    }
    const u32 myw = (u32)f2bf(hA) | ((u32)f2bf(hB) << 16);
    const u32 otherw = (u32)__shfl_down((int)myw, 1);
    if (!(up & 1)) {  // publish u64 covering local units 2up..2up+3
      u64 w64 = (u64)myw | ((u64)otherw << 32);
      u64* dst = (u64*)(hbuf + (size_t)(t + 1) * 16384 + (size_t)gb * 1024 +
                        g * 32 + up * 2);
      __hip_atomic_store(dst, w64, __ATOMIC_RELAXED, __HIP_MEMORY_SCOPE_AGENT);
    }
    ISSUE(t + 1);  // re-issue gather immediately (hbuf has 513 rows; t+1<=512 ok)
    gxv0 = gxn0;
    gxv1 = gxn1;
  }
#undef ISSUE
}

// ---------------- host ----------------

extern "C" void kernel_launch(void* const* d_in, const int* in_sizes, int n_in,
                              void* d_out, int out_size, void* d_ws, size_t ws_size,
                              hipStream_t stream) {
  const float* x        = (const float*)d_in[0];
  const float* mem      = (const float*)d_in[1];
  const float* src_bias = (const float*)d_in[2];
  const float* w_src_q = (const float*)d_in[4];  const float* b_src_q = (const float*)d_in[5];
  const float* w_src_k = (const float*)d_in[6];  const float* b_src_k = (const float*)d_in[7];
  const float* w_src_v = (const float*)d_in[8];  const float* b_src_v = (const float*)d_in[9];
  const float* w_src_o = (const float*)d_in[10]; const float* b_src_o = (const float*)d_in[11];
  const float* w_tgt_q = (const float*)d_in[12]; const float* b_tgt_q = (const float*)d_in[13];
  const float* w_tgt_k = (const float*)d_in[14]; const float* b_tgt_k = (const float*)d_in[15];
  const float* w_tgt_v = (const float*)d_in[16]; const float* b_tgt_v = (const float*)d_in[17];
  const float* w_tgt_o = (const float*)d_in[18]; const float* b_tgt_o = (const float*)d_in[19];
  const float* lstm_w  = (const float*)d_in[20]; const float* lstm_b  = (const float*)d_in[21];
  const float* w1 = (const float*)d_in[22]; const float* b1f = (const float*)d_in[23];
  const float* w2 = (const float*)d_in[24]; const float* b2f = (const float*)d_in[25];

  char* ws = (char*)d_ws;
  const size_t MiB = 1024ull * 1024ull;
  u16*   xcb  = (u16*)(ws + 0);             // [8192][2048]: cols 0-1023 x, 1024+ c
  u16*   wlp  = (u16*)(ws + 32 * MiB);      // [4096 packed][2048]
  u16*   whp  = (u16*)(ws + 48 * MiB);      // [4096 packed][1024]
  u16*   w1t  = (u16*)(ws + 56 * MiB);
  u16*   w2t  = (u16*)(ws + 64 * MiB);
  float* pb   = (float*)(ws + 72 * MiB);    // packed lstm bias [4096]
  u16*   hbuf = (u16*)(ws + 73 * MiB);      // [513][16][1024]
  u16*   memb = (u16*)(ws + 90 * MiB);
  u16*   wt[8];
  for (int i = 0; i < 8; ++i) wt[i] = (u16*)(ws + 106 * MiB + (size_t)i * 2 * MiB);
  u16*   bq   = (u16*)(ws + 122 * MiB);
  u16*   bk   = (u16*)(ws + 138 * MiB);
  u16*   bv   = (u16*)(ws + 154 * MiB);
  u16*   ao_s = (u16*)(ws + 170 * MiB);
  u16*   ao_t = (u16*)(ws + 186 * MiB);
  float* c32  = (float*)(ws + 202 * MiB);   // ..234
  float* gx   = (float*)(ws + 90 * MiB);    // overlay 90..218 (after attention)
  u16*   ffn1 = (u16*)(ws + 90 * MiB);      // overlay 90..154 (after scan)

  // sentinel-fill h rows 1..512 FIRST; scan polls via L2-bypass
  hipMemsetAsync(hbuf + 16384, 0xFF, (size_t)512 * 16384 * 2, stream);
  hipMemsetAsync(hbuf, 0, 32768, stream);   // h_0 = 0

  // --- conversions ---
  cvt_x_kernel<<<8192, 256, 0, stream>>>(xcb, x);
  cvt_bf16_kernel<<<8192, 256, 0, stream>>>(memb, mem, 2097152);
  const dim3 g1k(32, 32);
  convt_kernel<<<g1k, 256, 0, stream>>>(wt[0], w_src_q, 1024, 1024, 0, 0.125f);
  convt_kernel<<<g1k, 256, 0, stream>>>(wt[1], w_src_k, 1024, 1024, 0, 1.f);
  convt_kernel<<<g1k, 256, 0, stream>>>(wt[2], w_src_v, 1024, 1024, 0, 1.f);
  convt_kernel<<<g1k, 256, 0, stream>>>(wt[3], w_src_o, 1024, 1024, 0, 1.f);
  convt_kernel<<<g1k, 256, 0, stream>>>(wt[4], w_tgt_q, 1024, 1024, 0, 0.125f);
  convt_kernel<<<g1k, 256, 0, stream>>>(wt[5], w_tgt_k, 1024, 1024, 0, 1.f);
  convt_kernel<<<g1k, 256, 0, stream>>>(wt[6], w_tgt_v, 1024, 1024, 0, 1.f);
  convt_kernel<<<g1k, 256, 0, stream>>>(wt[7], w_tgt_o, 1024, 1024, 0, 1.f);
  convt_perm_kernel<<<dim3(32, 64, 4), 256, 0, stream>>>(wlp, lstm_w, 2048, 0);
  convt_perm_kernel<<<dim3(32, 32, 4), 256, 0, stream>>>(whp, lstm_w, 1024, 2048);
  convt_kernel<<<dim3(128, 32), 256, 0, stream>>>(w1t, w1, 1024, 4096, 0, 1.f);
  convt_kernel<<<dim3(32, 128), 256, 0, stream>>>(w2t, w2, 4096, 1024, 0, 1.f);
  pack_bias_kernel<<<16, 256, 0, stream>>>(pb, lstm_b);

  const dim3 gN1(8, 64);   // N=1024
  const dim3 gN4(32, 64);  // N=4096

  // --- src attention ---
  gemm_bt_kernel<1, 0, 0, 0><<<gN1, 256, 0, stream>>>(xcb, 2048, wt[0], b_src_q, 0.125f, bq, 1024, nullptr, 0, 1024);
  gemm_bt_kernel<1, 0, 0, 0><<<gN1, 256, 0, stream>>>(memb, 1024, wt[1], b_src_k, 1.f, bk, 1024, nullptr, 0, 1024);
  gemm_bt_kernel<1, 0, 0, 0><<<gN1, 256, 0, stream>>>(memb, 1024, wt[2], b_src_v, 1.f, bv, 1024, nullptr, 0, 1024);
  flash_kernel<0><<<dim3(8, 16, 16), 256, 0, stream>>>(bq, bk, bv, src_bias, ao_s);
  // --- tgt (causal self) attention ---
  gemm_bt_kernel<1, 0, 0, 0><<<gN1, 256, 0, stream>>>(xcb, 2048, wt[4], b_tgt_q, 0.125f, bq, 1024, nullptr, 0, 1024);
  gemm_bt_kernel<1, 0, 0, 0><<<gN1, 256, 0, stream>>>(xcb, 2048, wt[5], b_tgt_k, 1.f, bk, 1024, nullptr, 0, 1024);
  gemm_bt_kernel<1, 0, 0, 0><<<gN1, 256, 0, stream>>>(xcb, 2048, wt[6], b_tgt_v, 1.f, bv, 1024, nullptr, 0, 1024);
  flash_kernel<1><<<dim3(8, 16, 16), 256, 0, stream>>>(bq, bk, bv, nullptr, ao_t);
  // --- c = ao_s@Wo_s + bo_s + ao_t@Wo_t + bo_t -> xcb cols 1024+ (bf16) ---
  gemm_bt_kernel<0, 0, 0, 0><<<gN1, 256, 0, stream>>>(ao_s, 1024, wt[3], b_src_o, 1.f, c32, 1024, nullptr, 0, 1024);
  gemm_bt_kernel<1, 1, 0, 0><<<gN1, 256, 0, stream>>>(ao_t, 1024, wt[7], b_tgt_o, 1.f, xcb + 1024, 2048, c32, 1024, 1024);
  // --- gx = [x|c] @ wlp^T + pb  (K=2048, packed cols) ---
  gemm_bt_kernel<0, 0, 0, 0><<<gN4, 256, 0, stream>>>(xcb, 2048, wlp, pb, 1.f, gx, 4096, nullptr, 0, 2048);
  // --- LSTM scan: single persistent kernel, 32 WGs (all co-resident) ---
  lstm_scan_kernel<<<dim3(SCAN_NW), 256, 0, stream>>>(whp, gx, hbuf);
  // --- FFN ---
  gemm_bt_kernel<1, 0, 1, 0><<<gN4, 256, 0, stream>>>(hbuf + 16384, 1024, w1t, b1f, 1.f, ffn1, 4096, nullptr, 0, 1024);
  gemm_bt_kernel<0, 0, 0, 2><<<gN1, 256, 0, stream>>>(ffn1, 4096, w2t, b2f, 1.f, (float*)d_out, 1024, nullptr, 0, 4096);
}

// Round 11
// 2955.608 us; speedup vs baseline: 1.1001x; 1.1001x over previous
//
#include <hip/hip_runtime.h>
#include <hip/hip_bf16.h>
#include <stdint.h>

// ---------------------------------------------------------------------------
// DeepLSTMDecoderLayer R11 = R7 scan (best, 2035us) + [132] padding ONLY,
// plus non-scan work:
//  - tgt Q/K/V fused into one N=3072 GEMM (wt[4..6] contiguous); src K/V
//    fused N=2048; flash takes row-stride params; biases pre-packed+scaled.
//  - XCD-aware bijective block swizzle in gemm_bt (all grids %8==0).
// R10 lessons: tail-ISSUE + reload-before-sleep inflate L3 traffic (FETCH
// 141->171MB) and regress the scan; reverted. FFN1 fusion stays demoted (R9).
// ws layout (MiB): 0 xcb(32) | 32 wlp(16) | 48 whp(8) | 56 w1t(8) | 64 w2t(8)
//   | 72 pb/pb3/pb2 | 73 hbuf(16.04) | 90 memb(16)->gx/ffn1 overlay
//   | 106 wt[8](16) | 122 qsrc/qkv(48) | 170 ao_s | 186 ao_t | 202 c32(32)
// ---------------------------------------------------------------------------

typedef unsigned short u16;
typedef unsigned int u32;
typedef unsigned long long u64;
typedef __bf16 bf16x8 __attribute__((ext_vector_type(8)));
typedef float f32x4 __attribute__((ext_vector_type(4)));
typedef int int32x4 __attribute__((ext_vector_type(4)));
typedef unsigned long long u64x2 __attribute__((ext_vector_type(2)));

#define DEV static __device__ __forceinline__

DEV u16 f2bf(float x) {
  u32 u = __builtin_bit_cast(u32, x);
  u += 0x7FFF + ((u >> 16) & 1);  // round-to-nearest-even
  return (u16)(u >> 16);
}

DEV bf16x8 ldfrag(const void* p) {
  int32x4 v = *(const int32x4*)p;
  return __builtin_bit_cast(bf16x8, v);
}

DEV bf16x8 mkfrag(u64 lo, u64 hi) {
  u64x2 v;
  v.x = lo;
  v.y = hi;
  return __builtin_bit_cast(bf16x8, v);
}

DEV f32x4 mfma_bf16(bf16x8 a, bf16x8 b, f32x4 c) {
  return __builtin_amdgcn_mfma_f32_16x16x32_bf16(a, b, c, 0, 0, 0);
}

DEV u64 aload(const u64* p) {
  return __hip_atomic_load(p, __ATOMIC_RELAXED, __HIP_MEMORY_SCOPE_AGENT);
}

// async global->LDS, 16B per lane; LDS dest is wave-uniform base (+lane*16 HW)
DEV void load_lds16(const u16* g, u16* l) {
  __builtin_amdgcn_global_load_lds(
      (__attribute__((address_space(1))) void*)(uintptr_t)g,
      (__attribute__((address_space(3))) void*)(uintptr_t)l, 16, 0, 0);
}

// ---------------- conversion kernels ----------------

__global__ __launch_bounds__(256) void cvt_bf16_kernel(u16* __restrict__ out,
                                                       const float* __restrict__ in,
                                                       int n4) {
  int i = blockIdx.x * 256 + threadIdx.x;
  if (i >= n4) return;
  float4 v = ((const float4*)in)[i];
  ushort4 s;
  s.x = f2bf(v.x); s.y = f2bf(v.y); s.z = f2bf(v.z); s.w = f2bf(v.w);
  ((ushort4*)out)[i] = s;
}

// x[8192][1024] f32 -> xcb[r][0..1023] with row stride 2048
__global__ __launch_bounds__(256) void cvt_x_kernel(u16* __restrict__ out,
                                                    const float* __restrict__ in) {
  int i = blockIdx.x * 256 + threadIdx.x;
  int r = i >> 8, cg4 = i & 255;
  float4 v = ((const float4*)in)[i];
  ushort4 s;
  s.x = f2bf(v.x); s.y = f2bf(v.y); s.z = f2bf(v.z); s.w = f2bf(v.w);
  *(ushort4*)(out + (size_t)r * 2048 + cg4 * 4) = s;
}

// out[n*K + k] = in[(k+koff)*N + n] * scale
__global__ __launch_bounds__(256) void convt_kernel(u16* __restrict__ out,
                                                    const float* __restrict__ in,
                                                    int K, int N, int koff, float scale) {
  __shared__ float tile[32][33];
  const int tid = threadIdx.x;
  const int n0 = blockIdx.x * 32, k0 = blockIdx.y * 32;
  const int c = tid & 31, r = tid >> 5;
#pragma unroll
  for (int i = 0; i < 4; ++i)
    tile[r + i * 8][c] = in[(size_t)(k0 + r + i * 8 + koff) * N + n0 + c];
  __syncthreads();
#pragma unroll
  for (int i = 0; i < 4; ++i)
    out[(size_t)(n0 + r + i * 8) * K + k0 + c] = f2bf(tile[c][r + i * 8] * scale);
}

// packed LSTM weight: out[(u*4+g)*K + k] = lstm_w[(k+koff)*4096 + g*1024 + u]
__global__ __launch_bounds__(256) void convt_perm_kernel(u16* __restrict__ out,
                                                         const float* __restrict__ in,
                                                         int K, int koff) {
  __shared__ float tile[32][33];
  const int tid = threadIdx.x;
  const int u0 = blockIdx.x * 32, k0 = blockIdx.y * 32, g = blockIdx.z;
  const int c = tid & 31, r = tid >> 5;
#pragma unroll
  for (int i = 0; i < 4; ++i)
    tile[r + i * 8][c] = in[(size_t)(k0 + r + i * 8 + koff) * 4096 + g * 1024 + u0 + c];
  __syncthreads();
#pragma unroll
  for (int i = 0; i < 4; ++i)
    out[(size_t)((u0 + r + i * 8) * 4 + g) * K + k0 + c] = f2bf(tile[c][r + i * 8]);
}

__global__ __launch_bounds__(256) void pack_bias_kernel(float* __restrict__ out,
                                                        const float* __restrict__ in) {
  int p = blockIdx.x * 256 + threadIdx.x;  // 4096
  out[p] = in[(p & 3) * 1024 + (p >> 2)];
}

// concat bias: [b0*s0 | b1 | b2], grid chooses length (8 -> 2048, 12 -> 3072)
__global__ __launch_bounds__(256) void pack_bias3_kernel(
    float* __restrict__ out, const float* __restrict__ b0,
    const float* __restrict__ b1, const float* __restrict__ b2, float s0) {
  int p = blockIdx.x * 256 + threadIdx.x;
  float v = (p < 1024) ? b0[p] * s0 : (p < 2048 ? b1[p - 1024] : b2[p - 2048]);
  out[p] = v;
}

// ---------------- GEMM: C[M,N] = A[M,K] @ Bt[N,K]^T (+bias, +cacc, relu, perm)
// 128x128 tile, BK=32, global_load_lds staging, XCD-bijective block swizzle.
// grid (N/128, M/128), 256 thr. PERM==2: out row r -> (r&15)*512 + (r>>4)
template <int OUTBF, int ACCUM, int RELU, int PERM>
__global__ __launch_bounds__(256) void gemm_bt_kernel(
    const u16* __restrict__ A, int lda, const u16* __restrict__ Bt,
    const float* __restrict__ bias, float bscale,
    void* __restrict__ outp, int ostride,
    const float* __restrict__ cacc, int cstride, int K) {
  __shared__ u16 As[128 * 32];
  __shared__ u16 Bs[128 * 32];
  const int tid = threadIdx.x;
  const int wave = tid >> 6, lane = tid & 63;
  const int lr = lane & 15, lg = lane >> 4;
  // XCD-aware bijective swizzle (requires nwg%8==0; all launches satisfy)
  const int nwg = gridDim.x * gridDim.y;
  const int wgid = blockIdx.y * gridDim.x + blockIdx.x;
  const int swz = (wgid & 7) * (nwg >> 3) + (wgid >> 3);
  const int m0 = (swz / gridDim.x) * 128, n0 = (swz % gridDim.x) * 128;
  const int wr = (wave >> 1) * 64, wc = (wave & 1) * 64;

  f32x4 acc[4][4] = {};

  const int sr = lane >> 2, sce = (lane & 3) * 8;
  const u16* gA = A + (size_t)(m0 + wave * 16 + sr) * lda + sce;
  const u16* gB = Bt + (size_t)(n0 + wave * 16 + sr) * K + sce;
  u16* lA = As + wave * 16 * 32;
  u16* lB = Bs + wave * 16 * 32;

  for (int k0 = 0; k0 < K; k0 += 32) {
    __syncthreads();
    load_lds16(gA + k0, lA);
    load_lds16(gA + k0 + (size_t)64 * lda, lA + 64 * 32);
    load_lds16(gB + k0, lB);
    load_lds16(gB + k0 + (size_t)64 * K, lB + 64 * 32);
    __syncthreads();
    bf16x8 af[4], bfr[4];
    const u16* pa = As + (wr + lr) * 32 + lg * 8;
    const u16* pb = Bs + (wc + lr) * 32 + lg * 8;
#pragma unroll
    for (int i = 0; i < 4; ++i) af[i] = ldfrag(pa + i * 16 * 32);
#pragma unroll
    for (int j = 0; j < 4; ++j) bfr[j] = ldfrag(pb + j * 16 * 32);
#pragma unroll
    for (int i = 0; i < 4; ++i)
#pragma unroll
      for (int j = 0; j < 4; ++j)
        acc[i][j] = mfma_bf16(af[i], bfr[j], acc[i][j]);
  }

  const int col0 = n0 + wc + lr;
  const int row0 = m0 + wr + lg * 4;
#pragma unroll
  for (int i = 0; i < 4; ++i) {
#pragma unroll
    for (int j = 0; j < 4; ++j) {
      const int c = col0 + j * 16;
      const float bv = bias ? bias[c] * bscale : 0.f;
#pragma unroll
      for (int ii = 0; ii < 4; ++ii) {
        const int r = row0 + i * 16 + ii;
        float v = acc[i][j][ii] + bv;
        if (ACCUM) v += cacc[(size_t)r * cstride + c];
        if (RELU) v = fmaxf(v, 0.f);
        const int rp = (PERM == 2) ? ((r & 15) * 512 + (r >> 4)) : r;
        if (OUTBF) ((u16*)outp)[(size_t)rp * ostride + c] = f2bf(v);
        else       ((float*)outp)[(size_t)rp * ostride + c] = v;
      }
    }
  }
}

// ---------------- flash attention (R1-validated; + row strides) ----------------
template <int CAUSAL>
__global__ __launch_bounds__(256) void flash_kernel(
    const u16* __restrict__ Q, const u16* __restrict__ Kb, const u16* __restrict__ Vb,
    const float* __restrict__ sbias, u16* __restrict__ O, int qs, int ks) {
  __shared__ u16 Kl[64 * 72];
  __shared__ u16 Vt[64 * 72];
  __shared__ u16 Pl[64 * 72];
  const int tid = threadIdx.x, wave = tid >> 6, lane = tid & 63;
  const int lr = lane & 15, lg = lane >> 4;
  const int q0 = blockIdx.x * 64, hh = blockIdx.y, b = blockIdx.z;

  bf16x8 qf[2];
  {
    const u16* qp = Q + (size_t)(b * 512 + q0 + wave * 16 + lr) * qs + hh * 64 + lg * 8;
    qf[0] = ldfrag(qp);
    qf[1] = ldfrag(qp + 32);
  }
  f32x4 oacc[4] = {};
  float mrun[4], lsum[4];
#pragma unroll
  for (int ii = 0; ii < 4; ++ii) { mrun[ii] = -3e38f; lsum[ii] = 0.f; }

  const int ntiles = CAUSAL ? (q0 / 64 + 1) : 8;
  for (int ti = 0; ti < ntiles; ++ti) {
    const int s0 = ti * 64;
    {
      const int r = tid >> 2, ch = (tid & 3) * 16;
      const u16* kp = Kb + (size_t)(b * 512 + s0 + r) * ks + hh * 64 + ch;
      const u16* vp = Vb + (size_t)(b * 512 + s0 + r) * ks + hh * 64 + ch;
      int32x4 k0v = *(const int32x4*)kp;
      int32x4 k1v = *(const int32x4*)(kp + 8);
      int32x4 v0v = *(const int32x4*)vp;
      int32x4 v1v = *(const int32x4*)(vp + 8);
      *(int32x4*)&Kl[r * 72 + ch] = k0v;
      *(int32x4*)&Kl[r * 72 + ch + 8] = k1v;
      const u16* v0p = (const u16*)&v0v;
      const u16* v1p = (const u16*)&v1v;
#pragma unroll
      for (int j = 0; j < 8; ++j) {
        Vt[(ch + j) * 72 + r] = v0p[j];
        Vt[(ch + 8 + j) * 72 + r] = v1p[j];
      }
    }
    __syncthreads();
    f32x4 sf[4] = {};
#pragma unroll
    for (int j = 0; j < 4; ++j)
#pragma unroll
      for (int ks2 = 0; ks2 < 2; ++ks2) {
        bf16x8 kf = ldfrag(&Kl[(j * 16 + lr) * 72 + ks2 * 32 + lg * 8]);
        sf[j] = mfma_bf16(qf[ks2], kf, sf[j]);
      }
    if (!CAUSAL) {
#pragma unroll
      for (int j = 0; j < 4; ++j) {
        const float bv = sbias[b * 512 + s0 + j * 16 + lr];
#pragma unroll
        for (int ii = 0; ii < 4; ++ii) sf[j][ii] += bv;
      }
    } else {
#pragma unroll
      for (int j = 0; j < 4; ++j) {
        const int s = s0 + j * 16 + lr;
#pragma unroll
        for (int ii = 0; ii < 4; ++ii) {
          const int q = q0 + wave * 16 + lg * 4 + ii;
          if (s > q) sf[j][ii] -= 1e9f;
        }
      }
    }
    float sc[4], rs[4];
#pragma unroll
    for (int ii = 0; ii < 4; ++ii) {
      float m = fmaxf(fmaxf(sf[0][ii], sf[1][ii]), fmaxf(sf[2][ii], sf[3][ii]));
#pragma unroll
      for (int off = 1; off < 16; off <<= 1) m = fmaxf(m, __shfl_xor(m, off));
      const float mn = fmaxf(mrun[ii], m);
      sc[ii] = __expf(mrun[ii] - mn);
      mrun[ii] = mn;
      rs[ii] = 0.f;
    }
#pragma unroll
    for (int j = 0; j < 4; ++j)
#pragma unroll
      for (int ii = 0; ii < 4; ++ii) {
        const float p = __expf(sf[j][ii] - mrun[ii]);
        rs[ii] += p;
        Pl[(wave * 16 + lg * 4 + ii) * 72 + j * 16 + lr] = f2bf(p);
      }
#pragma unroll
    for (int ii = 0; ii < 4; ++ii) {
      float r = rs[ii];
#pragma unroll
      for (int off = 1; off < 16; off <<= 1) r += __shfl_xor(r, off);
      lsum[ii] = lsum[ii] * sc[ii] + r;
    }
#pragma unroll
    for (int df = 0; df < 4; ++df)
#pragma unroll
      for (int ii = 0; ii < 4; ++ii) oacc[df][ii] *= sc[ii];
    __syncthreads();
    bf16x8 pf[2];
    pf[0] = ldfrag(&Pl[(wave * 16 + lr) * 72 + lg * 8]);
    pf[1] = ldfrag(&Pl[(wave * 16 + lr) * 72 + 32 + lg * 8]);
#pragma unroll
    for (int df = 0; df < 4; ++df)
#pragma unroll
      for (int ks2 = 0; ks2 < 2; ++ks2) {
        bf16x8 vf = ldfrag(&Vt[(df * 16 + lr) * 72 + ks2 * 32 + lg * 8]);
        oacc[df] = mfma_bf16(pf[ks2], vf, oacc[df]);
      }
    __syncthreads();
  }
#pragma unroll
  for (int df = 0; df < 4; ++df)
#pragma unroll
    for (int ii = 0; ii < 4; ++ii) {
      const float v = oacc[df][ii] / lsum[ii];
      O[(size_t)(b * 512 + q0 + wave * 16 + lg * 4 + ii) * 1024 + hh * 64 + df * 16 + lr] =
          f2bf(v);
    }
}

// ---------------- persistent LSTM scan (R7-exact + [132] padding) ----------------
// 32 WGs x 256 thr (1/CU). WG g owns units [g*32,+32) = packed cols [g*128,+128).
// Split-K: wave w computes ALL 128 pcols over K in [w*256,+256); gathers its
// own 8KB of h(t) direct to regs (ISSUE at entry), spinning on sentinel
// (check -> sleep -> masked reload, as in R7). Partials -> parity LDS padded
// to 132 (gate reads conflict-free). ONE barrier/step. Publish: plain agent
// stores, no drain.
#define SCAN_NW 32
__global__ __launch_bounds__(256, 1) void lstm_scan_kernel(
    const u16* __restrict__ Whp, const float* __restrict__ gx,
    u16* __restrict__ hbuf) {
  const int tid = threadIdx.x, wave = tid >> 6, lane = tid & 63;
  const int lr = lane & 15, lg = lane >> 4;
  const int g = blockIdx.x;
  __shared__ float part[2][4][16][132];  // padded (R10: conflicts -> 0)
  const int gb = tid >> 4;               // gate-phase batch row 0..15
  const int up = tid & 15;               // gate-phase unit pair: 2up, 2up+1
  float cs0 = 0.f, cs1 = 0.f;
  const u64 SENT = 0xFFFFFFFFFFFFFFFFull;

  const u16* wbase = Whp + (size_t)(g * 128 + lr) * 1024 + wave * 256 + lg * 8;
  const float* gxp = gx + (size_t)gb * 512 * 4096 + g * 128 + up * 8;
  const size_t goff = (size_t)lr * 1024 + wave * 256 + lg * 8;

  for (int t = 0; t < 512; ++t) {
    // gx prefetch (independent of h), as R7
    const float4 gxv0 = *(const float4*)(gxp + (size_t)t * 4096);
    const float4 gxv1 = *(const float4*)(gxp + (size_t)t * 4096 + 4);
    // gather this wave's K-quarter of h(t): issue, then spin on sentinel
    const u16* hp = hbuf + (size_t)t * 16384 + goff;
    u64 hw[16];
#pragma unroll
    for (int kc = 0; kc < 8; ++kc) {
      hw[kc * 2] = aload((const u64*)(hp + kc * 32));
      hw[kc * 2 + 1] = aload((const u64*)(hp + kc * 32 + 4));
    }
    {
      int guard = 0;
      for (;;) {
        bool ok = true;
#pragma unroll
        for (int i = 0; i < 16; ++i) ok &= (hw[i] != SENT);
        if (__all((int)ok)) break;
        __builtin_amdgcn_s_sleep(4);
        if (++guard > (1 << 20)) break;  // insurance against hang
#pragma unroll
        for (int kc = 0; kc < 8; ++kc) {
          if (hw[kc * 2] == SENT)
            hw[kc * 2] = aload((const u64*)(hp + kc * 32));
          if (hw[kc * 2 + 1] == SENT)
            hw[kc * 2 + 1] = aload((const u64*)(hp + kc * 32 + 4));
        }
      }
    }
    // partial GEMM: this wave's K-quarter, all 128 pcols, 16 batches
    f32x4 acc[8] = {};
#pragma unroll
    for (int kc = 0; kc < 8; ++kc) {
      const bf16x8 hf = mkfrag(hw[kc * 2], hw[kc * 2 + 1]);
#pragma unroll
      for (int j = 0; j < 8; ++j)
        acc[j] = mfma_bf16(hf, ldfrag(wbase + j * 16 * 1024 + kc * 32), acc[j]);
    }
    const int p = t & 1;
#pragma unroll
    for (int j = 0; j < 8; ++j)
#pragma unroll
      for (int ii = 0; ii < 4; ++ii)
        part[p][wave][lg * 4 + ii][j * 16 + lr] = acc[j][ii];
    __syncthreads();  // the ONLY barrier per step (parity protects overlap)
    // gate phase: thread (gb, up) -> local units 2up, 2up+1
    float s[8];
#pragma unroll
    for (int k = 0; k < 8; ++k)
      s[k] = part[p][0][gb][up * 8 + k] + part[p][1][gb][up * 8 + k] +
             part[p][2][gb][up * 8 + k] + part[p][3][gb][up * 8 + k];
    float hA, hB;
    {
      const float si = s[0] + gxv0.x, sj = s[1] + gxv0.y;
      const float sf_ = s[2] + gxv0.z, so = s[3] + gxv0.w;
      const float ig = 1.f / (1.f + __expf(-si));
      const float jg = 1.f - 2.f / (__expf(2.f * sj) + 1.f);
      const float fg = 1.f / (1.f + __expf(-sf_));
      const float og = 1.f / (1.f + __expf(-so));
      cs0 = fg * cs0 + ig * jg;
      hA = og * (1.f - 2.f / (__expf(2.f * cs0) + 1.f));
    }
    {
      const float si = s[4] + gxv1.x, sj = s[5] + gxv1.y;
      const float sf_ = s[6] + gxv1.z, so = s[7] + gxv1.w;
      const float ig = 1.f / (1.f + __expf(-si));
      const float jg = 1.f - 2.f / (__expf(2.f * sj) + 1.f);
      const float fg = 1.f / (1.f + __expf(-sf_));
      const float og = 1.f / (1.f + __expf(-so));
      cs1 = fg * cs1 + ig * jg;
      hB = og * (1.f - 2.f / (__expf(2.f * cs1) + 1.f));
    }
    const u32 myw = (u32)f2bf(hA) | ((u32)f2bf(hB) << 16);
    const u32 otherw = (u32)__shfl_down((int)myw, 1);  // lane+1 = (gb, up+1)
    if (!(up & 1)) {  // publish u64 covering local units 2up..2up+3
      u64 w64 = (u64)myw | ((u64)otherw << 32);
      u64* dst = (u64*)(hbuf + (size_t)(t + 1) * 16384 + (size_t)gb * 1024 +
                        g * 32 + up * 2);
      __hip_atomic_store(dst, w64, __ATOMIC_RELAXED, __HIP_MEMORY_SCOPE_AGENT);
    }
    // no second barrier: next step writes parity p^1
  }
}

// ---------------- host ----------------

extern "C" void kernel_launch(void* const* d_in, const int* in_sizes, int n_in,
                              void* d_out, int out_size, void* d_ws, size_t ws_size,
                              hipStream_t stream) {
  const float* x        = (const float*)d_in[0];
  const float* mem      = (const float*)d_in[1];
  const float* src_bias = (const float*)d_in[2];
  const float* w_src_q = (const float*)d_in[4];  const float* b_src_q = (const float*)d_in[5];
  const float* w_src_k = (const float*)d_in[6];  const float* b_src_k = (const float*)d_in[7];
  const float* w_src_v = (const float*)d_in[8];  const float* b_src_v = (const float*)d_in[9];
  const float* w_src_o = (const float*)d_in[10]; const float* b_src_o = (const float*)d_in[11];
  const float* w_tgt_q = (const float*)d_in[12]; const float* b_tgt_q = (const float*)d_in[13];
  const float* w_tgt_k = (const float*)d_in[14]; const float* b_tgt_k = (const float*)d_in[15];
  const float* w_tgt_v = (const float*)d_in[16]; const float* b_tgt_v = (const float*)d_in[17];
  const float* w_tgt_o = (const float*)d_in[18]; const float* b_tgt_o = (const float*)d_in[19];
  const float* lstm_w  = (const float*)d_in[20]; const float* lstm_b  = (const float*)d_in[21];
  const float* w1 = (const float*)d_in[22]; const float* b1f = (const float*)d_in[23];
  const float* w2 = (const float*)d_in[24]; const float* b2f = (const float*)d_in[25];

  char* ws = (char*)d_ws;
  const size_t MiB = 1024ull * 1024ull;
  u16*   xcb  = (u16*)(ws + 0);             // [8192][2048]: cols 0-1023 x, 1024+ c
  u16*   wlp  = (u16*)(ws + 32 * MiB);      // [4096 packed][2048]
  u16*   whp  = (u16*)(ws + 48 * MiB);      // [4096 packed][1024]
  u16*   w1t  = (u16*)(ws + 56 * MiB);
  u16*   w2t  = (u16*)(ws + 64 * MiB);
  float* pb   = (float*)(ws + 72 * MiB);    // packed lstm bias [4096]
  float* pb3  = pb + 4096;                  // tgt qkv bias [3072] (q pre-scaled)
  float* pb2  = pb3 + 3072;                 // src kv bias [2048]
  u16*   hbuf = (u16*)(ws + 73 * MiB);      // [513][16][1024]
  u16*   memb = (u16*)(ws + 90 * MiB);
  u16*   wt[8];
  for (int i = 0; i < 8; ++i) wt[i] = (u16*)(ws + 106 * MiB + (size_t)i * 2 * MiB);
  u16*   qsrc = (u16*)(ws + 122 * MiB);     // [8192][1024]
  u16*   kvs  = (u16*)(ws + 138 * MiB);     // [8192][2048] (src K|V)
  u16*   qkv  = (u16*)(ws + 122 * MiB);     // [8192][3072] (tgt Q|K|V, reuse)
  u16*   ao_s = (u16*)(ws + 170 * MiB);
  u16*   ao_t = (u16*)(ws + 186 * MiB);
  float* c32  = (float*)(ws + 202 * MiB);   // ..234
  float* gx   = (float*)(ws + 90 * MiB);    // overlay 90..218 (after attention)
  u16*   ffn1 = (u16*)(ws + 90 * MiB);      // overlay 90..154 (after scan)

  // sentinel-fill h rows 1..512 FIRST; scan polls via L2-bypass
  hipMemsetAsync(hbuf + 16384, 0xFF, (size_t)512 * 16384 * 2, stream);
  hipMemsetAsync(hbuf, 0, 32768, stream);   // h_0 = 0

  // --- conversions ---
  cvt_x_kernel<<<8192, 256, 0, stream>>>(xcb, x);
  cvt_bf16_kernel<<<8192, 256, 0, stream>>>(memb, mem, 2097152);
  const dim3 g1k(32, 32);
  convt_kernel<<<g1k, 256, 0, stream>>>(wt[0], w_src_q, 1024, 1024, 0, 0.125f);
  convt_kernel<<<g1k, 256, 0, stream>>>(wt[1], w_src_k, 1024, 1024, 0, 1.f);
  convt_kernel<<<g1k, 256, 0, stream>>>(wt[2], w_src_v, 1024, 1024, 0, 1.f);
  convt_kernel<<<g1k, 256, 0, stream>>>(wt[3], w_src_o, 1024, 1024, 0, 1.f);
  convt_kernel<<<g1k, 256, 0, stream>>>(wt[4], w_tgt_q, 1024, 1024, 0, 0.125f);
  convt_kernel<<<g1k, 256, 0, stream>>>(wt[5], w_tgt_k, 1024, 1024, 0, 1.f);
  convt_kernel<<<g1k, 256, 0, stream>>>(wt[6], w_tgt_v, 1024, 1024, 0, 1.f);
  convt_kernel<<<g1k, 256, 0, stream>>>(wt[7], w_tgt_o, 1024, 1024, 0, 1.f);
  convt_perm_kernel<<<dim3(32, 64, 4), 256, 0, stream>>>(wlp, lstm_w, 2048, 0);
  convt_perm_kernel<<<dim3(32, 32, 4), 256, 0, stream>>>(whp, lstm_w, 1024, 2048);
  convt_kernel<<<dim3(128, 32), 256, 0, stream>>>(w1t, w1, 1024, 4096, 0, 1.f);
  convt_kernel<<<dim3(32, 128), 256, 0, stream>>>(w2t, w2, 4096, 1024, 0, 1.f);
  pack_bias_kernel<<<16, 256, 0, stream>>>(pb, lstm_b);
  pack_bias3_kernel<<<12, 256, 0, stream>>>(pb3, b_tgt_q, b_tgt_k, b_tgt_v, 0.125f);
  pack_bias3_kernel<<<8, 256, 0, stream>>>(pb2, b_src_k, b_src_v, b_src_v, 1.f);

  // --- src attention: Q (N=1024) + fused K|V (N=2048) ---
  gemm_bt_kernel<1, 0, 0, 0><<<dim3(8, 64), 256, 0, stream>>>(xcb, 2048, wt[0], b_src_q, 0.125f, qsrc, 1024, nullptr, 0, 1024);
  gemm_bt_kernel<1, 0, 0, 0><<<dim3(16, 64), 256, 0, stream>>>(memb, 1024, wt[1], pb2, 1.f, kvs, 2048, nullptr, 0, 1024);
  flash_kernel<0><<<dim3(8, 16, 16), 256, 0, stream>>>(qsrc, kvs, kvs + 1024, src_bias, ao_s, 1024, 2048);
  // --- tgt (causal self) attention: fused Q|K|V (N=3072, wt[4..6] contiguous)
  gemm_bt_kernel<1, 0, 0, 0><<<dim3(24, 64), 256, 0, stream>>>(xcb, 2048, wt[4], pb3, 1.f, qkv, 3072, nullptr, 0, 1024);
  flash_kernel<1><<<dim3(8, 16, 16), 256, 0, stream>>>(qkv, qkv + 1024, qkv + 2048, nullptr, ao_t, 3072, 3072);
  // --- c = ao_s@Wo_s + bo_s + ao_t@Wo_t + bo_t -> xcb cols 1024+ (bf16) ---
  gemm_bt_kernel<0, 0, 0, 0><<<dim3(8, 64), 256, 0, stream>>>(ao_s, 1024, wt[3], b_src_o, 1.f, c32, 1024, nullptr, 0, 1024);
  gemm_bt_kernel<1, 1, 0, 0><<<dim3(8, 64), 256, 0, stream>>>(ao_t, 1024, wt[7], b_tgt_o, 1.f, xcb + 1024, 2048, c32, 1024, 1024);
  // --- gx = [x|c] @ wlp^T + pb  (K=2048, packed cols) ---
  gemm_bt_kernel<0, 0, 0, 0><<<dim3(32, 64), 256, 0, stream>>>(xcb, 2048, wlp, pb, 1.f, gx, 4096, nullptr, 0, 2048);
  // --- LSTM scan: single persistent kernel, 32 WGs (all co-resident) ---
  lstm_scan_kernel<<<dim3(SCAN_NW), 256, 0, stream>>>(whp, gx, hbuf);
  // --- FFN ---
  gemm_bt_kernel<1, 0, 1, 0><<<dim3(32, 64), 256, 0, stream>>>(hbuf + 16384, 1024, w1t, b1f, 1.f, ffn1, 4096, nullptr, 0, 1024);
  gemm_bt_kernel<0, 0, 0, 2><<<dim3(8, 64), 256, 0, stream>>>(ffn1, 4096, w2t, b2f, 1.f, (float*)d_out, 1024, nullptr, 0, 4096);
}

// Round 12
// 2950.298 us; speedup vs baseline: 1.1020x; 1.0018x over previous
//
#include <hip/hip_runtime.h>
#include <hip/hip_bf16.h>
#include <stdint.h>

// ---------------------------------------------------------------------------
// DeepLSTMDecoderLayer R12 = R11 + consolidation:
//  - gx in bf16 (halves gx write + scan gx stream; margin 4.8x covers it)
//  - c-projection fused: ONE K=2048 GEMM over [ao_s|ao_t] (no c32 roundtrip)
//  - x-side projections fused: ONE N=4096 GEMM (srcQ|tgtQ|tgtK|tgtV)
//  - scan: s_sleep(4)->(2) only; otherwise byte-identical to R11 (2023us)
// Layout (MiB), peak 234 (proven >=248):
//  0 xcb(32) | 32 wlp(16) | 48 whp(8) | 56 w1t(8) | 64 w2t(8)
//  | 72 pb/pbq4/pb2/pbo | 73 hbuf(17) | 90 memb(16) -> aot2(32) -> gx bf16(64)
//  | 122 qx4(64) | 186 kvs(32) | 218 wqt4(8)+wkv2(4)+wo2(4)
//  | ffn1(64) @154 post-scan (over dead qx4/kvs)
// ---------------------------------------------------------------------------

typedef unsigned short u16;
typedef unsigned int u32;
typedef unsigned long long u64;
typedef __bf16 bf16x8 __attribute__((ext_vector_type(8)));
typedef float f32x4 __attribute__((ext_vector_type(4)));
typedef int int32x4 __attribute__((ext_vector_type(4)));
typedef unsigned long long u64x2 __attribute__((ext_vector_type(2)));
typedef unsigned short u16x8 __attribute__((ext_vector_type(8)));

#define DEV static __device__ __forceinline__

DEV u16 f2bf(float x) {
  u32 u = __builtin_bit_cast(u32, x);
  u += 0x7FFF + ((u >> 16) & 1);  // round-to-nearest-even
  return (u16)(u >> 16);
}

DEV bf16x8 ldfrag(const void* p) {
  int32x4 v = *(const int32x4*)p;
  return __builtin_bit_cast(bf16x8, v);
}

DEV bf16x8 mkfrag(u64 lo, u64 hi) {
  u64x2 v;
  v.x = lo;
  v.y = hi;
  return __builtin_bit_cast(bf16x8, v);
}

DEV f32x4 mfma_bf16(bf16x8 a, bf16x8 b, f32x4 c) {
  return __builtin_amdgcn_mfma_f32_16x16x32_bf16(a, b, c, 0, 0, 0);
}

DEV u64 aload(const u64* p) {
  return __hip_atomic_load(p, __ATOMIC_RELAXED, __HIP_MEMORY_SCOPE_AGENT);
}

// async global->LDS, 16B per lane; LDS dest is wave-uniform base (+lane*16 HW)
DEV void load_lds16(const u16* g, u16* l) {
  __builtin_amdgcn_global_load_lds(
      (__attribute__((address_space(1))) void*)(uintptr_t)g,
      (__attribute__((address_space(3))) void*)(uintptr_t)l, 16, 0, 0);
}

// ---------------- conversion kernels ----------------

__global__ __launch_bounds__(256) void cvt_bf16_kernel(u16* __restrict__ out,
                                                       const float* __restrict__ in,
                                                       int n4) {
  int i = blockIdx.x * 256 + threadIdx.x;
  if (i >= n4) return;
  float4 v = ((const float4*)in)[i];
  ushort4 s;
  s.x = f2bf(v.x); s.y = f2bf(v.y); s.z = f2bf(v.z); s.w = f2bf(v.w);
  ((ushort4*)out)[i] = s;
}

// x[8192][1024] f32 -> xcb[r][0..1023] with row stride 2048
__global__ __launch_bounds__(256) void cvt_x_kernel(u16* __restrict__ out,
                                                    const float* __restrict__ in) {
  int i = blockIdx.x * 256 + threadIdx.x;
  int r = i >> 8, cg4 = i & 255;
  float4 v = ((const float4*)in)[i];
  ushort4 s;
  s.x = f2bf(v.x); s.y = f2bf(v.y); s.z = f2bf(v.z); s.w = f2bf(v.w);
  *(ushort4*)(out + (size_t)r * 2048 + cg4 * 4) = s;
}

// out[n*K + k] = in[(k+koff)*N + n] * scale  (grid (N/32, 32) covers k<1024)
__global__ __launch_bounds__(256) void convt_kernel(u16* __restrict__ out,
                                                    const float* __restrict__ in,
                                                    int K, int N, int koff, float scale) {
  __shared__ float tile[32][33];
  const int tid = threadIdx.x;
  const int n0 = blockIdx.x * 32, k0 = blockIdx.y * 32;
  const int c = tid & 31, r = tid >> 5;
#pragma unroll
  for (int i = 0; i < 4; ++i)
    tile[r + i * 8][c] = in[(size_t)(k0 + r + i * 8 + koff) * N + n0 + c];
  __syncthreads();
#pragma unroll
  for (int i = 0; i < 4; ++i)
    out[(size_t)(n0 + r + i * 8) * K + k0 + c] = f2bf(tile[c][r + i * 8] * scale);
}

// packed LSTM weight: out[(u*4+g)*K + k] = lstm_w[(k+koff)*4096 + g*1024 + u]
__global__ __launch_bounds__(256) void convt_perm_kernel(u16* __restrict__ out,
                                                         const float* __restrict__ in,
                                                         int K, int koff) {
  __shared__ float tile[32][33];
  const int tid = threadIdx.x;
  const int u0 = blockIdx.x * 32, k0 = blockIdx.y * 32, g = blockIdx.z;
  const int c = tid & 31, r = tid >> 5;
#pragma unroll
  for (int i = 0; i < 4; ++i)
    tile[r + i * 8][c] = in[(size_t)(k0 + r + i * 8 + koff) * 4096 + g * 1024 + u0 + c];
  __syncthreads();
#pragma unroll
  for (int i = 0; i < 4; ++i)
    out[(size_t)((u0 + r + i * 8) * 4 + g) * K + k0 + c] = f2bf(tile[c][r + i * 8]);
}

__global__ __launch_bounds__(256) void pack_bias_kernel(float* __restrict__ out,
                                                        const float* __restrict__ in) {
  int p = blockIdx.x * 256 + threadIdx.x;  // 4096
  out[p] = in[(p & 3) * 1024 + (p >> 2)];
}

// [a*s | b] (grid 8 -> 2048)
__global__ __launch_bounds__(256) void pack_bias2_kernel(
    float* __restrict__ out, const float* __restrict__ a,
    const float* __restrict__ b, float s) {
  int p = blockIdx.x * 256 + threadIdx.x;
  out[p] = (p < 1024) ? a[p] * s : b[p - 1024];
}

// [a*s | b*s | c | d] (grid 16 -> 4096)
__global__ __launch_bounds__(256) void pack_bias4_kernel(
    float* __restrict__ out, const float* __restrict__ a,
    const float* __restrict__ b, const float* __restrict__ c,
    const float* __restrict__ d, float s) {
  int p = blockIdx.x * 256 + threadIdx.x;
  float v = (p < 1024)   ? a[p] * s
            : (p < 2048) ? b[p - 1024] * s
            : (p < 3072) ? c[p - 2048]
                         : d[p - 3072];
  out[p] = v;
}

__global__ __launch_bounds__(256) void bias_sum_kernel(float* __restrict__ out,
                                                       const float* __restrict__ a,
                                                       const float* __restrict__ b) {
  int p = blockIdx.x * 256 + threadIdx.x;  // 1024
  out[p] = a[p] + b[p];
}

// ---------------- GEMM: C[M,N] = A[M,K] @ Bt[N,K]^T (+bias, relu, perm)
// 128x128 tile, BK=32, global_load_lds staging, XCD-bijective block swizzle.
// grid (N/128, M/128), 256 thr. PERM==2: out row r -> (r&15)*512 + (r>>4)
template <int OUTBF, int RELU, int PERM>
__global__ __launch_bounds__(256) void gemm_bt_kernel(
    const u16* __restrict__ A, int lda, const u16* __restrict__ Bt,
    const float* __restrict__ bias, void* __restrict__ outp, int ostride, int K) {
  __shared__ u16 As[128 * 32];
  __shared__ u16 Bs[128 * 32];
  const int tid = threadIdx.x;
  const int wave = tid >> 6, lane = tid & 63;
  const int lr = lane & 15, lg = lane >> 4;
  const int nwg = gridDim.x * gridDim.y;
  const int wgid = blockIdx.y * gridDim.x + blockIdx.x;
  const int swz = (wgid & 7) * (nwg >> 3) + (wgid >> 3);
  const int m0 = (swz / gridDim.x) * 128, n0 = (swz % gridDim.x) * 128;
  const int wr = (wave >> 1) * 64, wc = (wave & 1) * 64;

  f32x4 acc[4][4] = {};

  const int sr = lane >> 2, sce = (lane & 3) * 8;
  const u16* gA = A + (size_t)(m0 + wave * 16 + sr) * lda + sce;
  const u16* gB = Bt + (size_t)(n0 + wave * 16 + sr) * K + sce;
  u16* lA = As + wave * 16 * 32;
  u16* lB = Bs + wave * 16 * 32;

  for (int k0 = 0; k0 < K; k0 += 32) {
    __syncthreads();
    load_lds16(gA + k0, lA);
    load_lds16(gA + k0 + (size_t)64 * lda, lA + 64 * 32);
    load_lds16(gB + k0, lB);
    load_lds16(gB + k0 + (size_t)64 * K, lB + 64 * 32);
    __syncthreads();
    bf16x8 af[4], bfr[4];
    const u16* pa = As + (wr + lr) * 32 + lg * 8;
    const u16* pb = Bs + (wc + lr) * 32 + lg * 8;
#pragma unroll
    for (int i = 0; i < 4; ++i) af[i] = ldfrag(pa + i * 16 * 32);
#pragma unroll
    for (int j = 0; j < 4; ++j) bfr[j] = ldfrag(pb + j * 16 * 32);
#pragma unroll
    for (int i = 0; i < 4; ++i)
#pragma unroll
      for (int j = 0; j < 4; ++j)
        acc[i][j] = mfma_bf16(af[i], bfr[j], acc[i][j]);
  }

  const int col0 = n0 + wc + lr;
  const int row0 = m0 + wr + lg * 4;
#pragma unroll
  for (int i = 0; i < 4; ++i) {
#pragma unroll
    for (int j = 0; j < 4; ++j) {
      const int c = col0 + j * 16;
      const float bv = bias ? bias[c] : 0.f;
#pragma unroll
      for (int ii = 0; ii < 4; ++ii) {
        const int r = row0 + i * 16 + ii;
        float v = acc[i][j][ii] + bv;
        if (RELU) v = fmaxf(v, 0.f);
        const int rp = (PERM == 2) ? ((r & 15) * 512 + (r >> 4)) : r;
        if (OUTBF) ((u16*)outp)[(size_t)rp * ostride + c] = f2bf(v);
        else       ((float*)outp)[(size_t)rp * ostride + c] = v;
      }
    }
  }
}

// ---------------- flash attention (R1-validated; strides for Q/K/O) ----------------
template <int CAUSAL>
__global__ __launch_bounds__(256) void flash_kernel(
    const u16* __restrict__ Q, const u16* __restrict__ Kb, const u16* __restrict__ Vb,
    const float* __restrict__ sbias, u16* __restrict__ O, int qs, int ks, int ost) {
  __shared__ u16 Kl[64 * 72];
  __shared__ u16 Vt[64 * 72];
  __shared__ u16 Pl[64 * 72];
  const int tid = threadIdx.x, wave = tid >> 6, lane = tid & 63;
  const int lr = lane & 15, lg = lane >> 4;
  const int q0 = blockIdx.x * 64, hh = blockIdx.y, b = blockIdx.z;

  bf16x8 qf[2];
  {
    const u16* qp = Q + (size_t)(b * 512 + q0 + wave * 16 + lr) * qs + hh * 64 + lg * 8;
    qf[0] = ldfrag(qp);
    qf[1] = ldfrag(qp + 32);
  }
  f32x4 oacc[4] = {};
  float mrun[4], lsum[4];
#pragma unroll
  for (int ii = 0; ii < 4; ++ii) { mrun[ii] = -3e38f; lsum[ii] = 0.f; }

  const int ntiles = CAUSAL ? (q0 / 64 + 1) : 8;
  for (int ti = 0; ti < ntiles; ++ti) {
    const int s0 = ti * 64;
    {
      const int r = tid >> 2, ch = (tid & 3) * 16;
      const u16* kp = Kb + (size_t)(b * 512 + s0 + r) * ks + hh * 64 + ch;
      const u16* vp = Vb + (size_t)(b * 512 + s0 + r) * ks + hh * 64 + ch;
      int32x4 k0v = *(const int32x4*)kp;
      int32x4 k1v = *(const int32x4*)(kp + 8);
      int32x4 v0v = *(const int32x4*)vp;
      int32x4 v1v = *(const int32x4*)(vp + 8);
      *(int32x4*)&Kl[r * 72 + ch] = k0v;
      *(int32x4*)&Kl[r * 72 + ch + 8] = k1v;
      const u16* v0p = (const u16*)&v0v;
      const u16* v1p = (const u16*)&v1v;
#pragma unroll
      for (int j = 0; j < 8; ++j) {
        Vt[(ch + j) * 72 + r] = v0p[j];
        Vt[(ch + 8 + j) * 72 + r] = v1p[j];
      }
    }
    __syncthreads();
    f32x4 sf[4] = {};
#pragma unroll
    for (int j = 0; j < 4; ++j)
#pragma unroll
      for (int ks2 = 0; ks2 < 2; ++ks2) {
        bf16x8 kf = ldfrag(&Kl[(j * 16 + lr) * 72 + ks2 * 32 + lg * 8]);
        sf[j] = mfma_bf16(qf[ks2], kf, sf[j]);
      }
    if (!CAUSAL) {
#pragma unroll
      for (int j = 0; j < 4; ++j) {
        const float bv = sbias[b * 512 + s0 + j * 16 + lr];
#pragma unroll
        for (int ii = 0; ii < 4; ++ii) sf[j][ii] += bv;
      }
    } else {
#pragma unroll
      for (int j = 0; j < 4; ++j) {
        const int s = s0 + j * 16 + lr;
#pragma unroll
        for (int ii = 0; ii < 4; ++ii) {
          const int q = q0 + wave * 16 + lg * 4 + ii;
          if (s > q) sf[j][ii] -= 1e9f;
        }
      }
    }
    float sc[4], rs[4];
#pragma unroll
    for (int ii = 0; ii < 4; ++ii) {
      float m = fmaxf(fmaxf(sf[0][ii], sf[1][ii]), fmaxf(sf[2][ii], sf[3][ii]));
#pragma unroll
      for (int off = 1; off < 16; off <<= 1) m = fmaxf(m, __shfl_xor(m, off));
      const float mn = fmaxf(mrun[ii], m);
      sc[ii] = __expf(mrun[ii] - mn);
      mrun[ii] = mn;
      rs[ii] = 0.f;
    }
#pragma unroll
    for (int j = 0; j < 4; ++j)
#pragma unroll
      for (int ii = 0; ii < 4; ++ii) {
        const float p = __expf(sf[j][ii] - mrun[ii]);
        rs[ii] += p;
        Pl[(wave * 16 + lg * 4 + ii) * 72 + j * 16 + lr] = f2bf(p);
      }
#pragma unroll
    for (int ii = 0; ii < 4; ++ii) {
      float r = rs[ii];
#pragma unroll
      for (int off = 1; off < 16; off <<= 1) r += __shfl_xor(r, off);
      lsum[ii] = lsum[ii] * sc[ii] + r;
    }
#pragma unroll
    for (int df = 0; df < 4; ++df)
#pragma unroll
      for (int ii = 0; ii < 4; ++ii) oacc[df][ii] *= sc[ii];
    __syncthreads();
    bf16x8 pf[2];
    pf[0] = ldfrag(&Pl[(wave * 16 + lr) * 72 + lg * 8]);
    pf[1] = ldfrag(&Pl[(wave * 16 + lr) * 72 + 32 + lg * 8]);
#pragma unroll
    for (int df = 0; df < 4; ++df)
#pragma unroll
      for (int ks2 = 0; ks2 < 2; ++ks2) {
        bf16x8 vf = ldfrag(&Vt[(df * 16 + lr) * 72 + ks2 * 32 + lg * 8]);
        oacc[df] = mfma_bf16(pf[ks2], vf, oacc[df]);
      }
    __syncthreads();
  }
#pragma unroll
  for (int df = 0; df < 4; ++df)
#pragma unroll
    for (int ii = 0; ii < 4; ++ii) {
      const float v = oacc[df][ii] / lsum[ii];
      O[(size_t)(b * 512 + q0 + wave * 16 + lg * 4 + ii) * ost + hh * 64 + df * 16 + lr] =
          f2bf(v);
    }
}

// ---------------- persistent LSTM scan (R11 + gx-bf16 + sleep(2)) ----------------
#define SCAN_NW 32
__global__ __launch_bounds__(256, 1) void lstm_scan_kernel(
    const u16* __restrict__ Whp, const u16* __restrict__ gxb,
    u16* __restrict__ hbuf) {
  const int tid = threadIdx.x, wave = tid >> 6, lane = tid & 63;
  const int lr = lane & 15, lg = lane >> 4;
  const int g = blockIdx.x;
  __shared__ float part[2][4][16][132];  // padded (conflicts -> 0, R11)
  const int gb = tid >> 4;               // gate-phase batch row 0..15
  const int up = tid & 15;               // gate-phase unit pair: 2up, 2up+1
  float cs0 = 0.f, cs1 = 0.f;
  const u64 SENT = 0xFFFFFFFFFFFFFFFFull;

  const u16* wbase = Whp + (size_t)(g * 128 + lr) * 1024 + wave * 256 + lg * 8;
  const u16* gxp = gxb + (size_t)gb * 512 * 4096 + g * 128 + up * 8;
  const size_t goff = (size_t)lr * 1024 + wave * 256 + lg * 8;

  for (int t = 0; t < 512; ++t) {
    // gx prefetch (bf16x8, independent of h)
    const bf16x8 gxv = ldfrag(gxp + (size_t)t * 4096);
    // gather this wave's K-quarter of h(t): issue, then spin on sentinel
    const u16* hp = hbuf + (size_t)t * 16384 + goff;
    u64 hw[16];
#pragma unroll
    for (int kc = 0; kc < 8; ++kc) {
      hw[kc * 2] = aload((const u64*)(hp + kc * 32));
      hw[kc * 2 + 1] = aload((const u64*)(hp + kc * 32 + 4));
    }
    {
      int guard = 0;
      for (;;) {
        bool ok = true;
#pragma unroll
        for (int i = 0; i < 16; ++i) ok &= (hw[i] != SENT);
        if (__all((int)ok)) break;
        __builtin_amdgcn_s_sleep(2);
        if (++guard > (1 << 20)) break;  // insurance against hang
#pragma unroll
        for (int kc = 0; kc < 8; ++kc) {
          if (hw[kc * 2] == SENT)
            hw[kc * 2] = aload((const u64*)(hp + kc * 32));
          if (hw[kc * 2 + 1] == SENT)
            hw[kc * 2 + 1] = aload((const u64*)(hp + kc * 32 + 4));
        }
      }
    }
    // partial GEMM: this wave's K-quarter, all 128 pcols, 16 batches
    f32x4 acc[8] = {};
#pragma unroll
    for (int kc = 0; kc < 8; ++kc) {
      const bf16x8 hf = mkfrag(hw[kc * 2], hw[kc * 2 + 1]);
#pragma unroll
      for (int j = 0; j < 8; ++j)
        acc[j] = mfma_bf16(hf, ldfrag(wbase + j * 16 * 1024 + kc * 32), acc[j]);
    }
    const int p = t & 1;
#pragma unroll
    for (int j = 0; j < 8; ++j)
#pragma unroll
      for (int ii = 0; ii < 4; ++ii)
        part[p][wave][lg * 4 + ii][j * 16 + lr] = acc[j][ii];
    __syncthreads();  // the ONLY barrier per step (parity protects overlap)
    // gate phase: thread (gb, up) -> local units 2up, 2up+1
    float s[8];
#pragma unroll
    for (int k = 0; k < 8; ++k)
      s[k] = part[p][0][gb][up * 8 + k] + part[p][1][gb][up * 8 + k] +
             part[p][2][gb][up * 8 + k] + part[p][3][gb][up * 8 + k];
    const u16x8 gq = __builtin_bit_cast(u16x8, gxv);
    float gxf[8];
#pragma unroll
    for (int k = 0; k < 8; ++k)
      gxf[k] = __builtin_bit_cast(float, (u32)((u32)gq[k] << 16));
    float hA, hB;
    {
      const float si = s[0] + gxf[0], sj = s[1] + gxf[1];
      const float sf_ = s[2] + gxf[2], so = s[3] + gxf[3];
      const float ig = 1.f / (1.f + __expf(-si));
      const float jg = 1.f - 2.f / (__expf(2.f * sj) + 1.f);
      const float fg = 1.f / (1.f + __expf(-sf_));
      const float og = 1.f / (1.f + __expf(-so));
      cs0 = fg * cs0 + ig * jg;
      hA = og * (1.f - 2.f / (__expf(2.f * cs0) + 1.f));
    }
    {
      const float si = s[4] + gxf[4], sj = s[5] + gxf[5];
      const float sf_ = s[6] + gxf[6], so = s[7] + gxf[7];
      const float ig = 1.f / (1.f + __expf(-si));
      const float jg = 1.f - 2.f / (__expf(2.f * sj) + 1.f);
      const float fg = 1.f / (1.f + __expf(-sf_));
      const float og = 1.f / (1.f + __expf(-so));
      cs1 = fg * cs1 + ig * jg;
      hB = og * (1.f - 2.f / (__expf(2.f * cs1) + 1.f));
    }
    const u32 myw = (u32)f2bf(hA) | ((u32)f2bf(hB) << 16);
    const u32 otherw = (u32)__shfl_down((int)myw, 1);  // lane+1 = (gb, up+1)
    if (!(up & 1)) {  // publish u64 covering local units 2up..2up+3
      u64 w64 = (u64)myw | ((u64)otherw << 32);
      u64* dst = (u64*)(hbuf + (size_t)(t + 1) * 16384 + (size_t)gb * 1024 +
                        g * 32 + up * 2);
      __hip_atomic_store(dst, w64, __ATOMIC_RELAXED, __HIP_MEMORY_SCOPE_AGENT);
    }
  }
}

// ---------------- host ----------------

extern "C" void kernel_launch(void* const* d_in, const int* in_sizes, int n_in,
                              void* d_out, int out_size, void* d_ws, size_t ws_size,
                              hipStream_t stream) {
  const float* x        = (const float*)d_in[0];
  const float* mem      = (const float*)d_in[1];
  const float* src_bias = (const float*)d_in[2];
  const float* w_src_q = (const float*)d_in[4];  const float* b_src_q = (const float*)d_in[5];
  const float* w_src_k = (const float*)d_in[6];  const float* b_src_k = (const float*)d_in[7];
  const float* w_src_v = (const float*)d_in[8];  const float* b_src_v = (const float*)d_in[9];
  const float* w_src_o = (const float*)d_in[10]; const float* b_src_o = (const float*)d_in[11];
  const float* w_tgt_q = (const float*)d_in[12]; const float* b_tgt_q = (const float*)d_in[13];
  const float* w_tgt_k = (const float*)d_in[14]; const float* b_tgt_k = (const float*)d_in[15];
  const float* w_tgt_v = (const float*)d_in[16]; const float* b_tgt_v = (const float*)d_in[17];
  const float* w_tgt_o = (const float*)d_in[18]; const float* b_tgt_o = (const float*)d_in[19];
  const float* lstm_w  = (const float*)d_in[20]; const float* lstm_b  = (const float*)d_in[21];
  const float* w1 = (const float*)d_in[22]; const float* b1f = (const float*)d_in[23];
  const float* w2 = (const float*)d_in[24]; const float* b2f = (const float*)d_in[25];

  char* ws = (char*)d_ws;
  const size_t MiB = 1024ull * 1024ull;
  u16*   xcb  = (u16*)(ws + 0);             // [8192][2048]: cols 0-1023 x, 1024+ c
  u16*   wlp  = (u16*)(ws + 32 * MiB);      // [4096 packed][2048]
  u16*   whp  = (u16*)(ws + 48 * MiB);      // [4096 packed][1024]
  u16*   w1t  = (u16*)(ws + 56 * MiB);
  u16*   w2t  = (u16*)(ws + 64 * MiB);
  float* pb   = (float*)(ws + 72 * MiB);    // packed lstm bias [4096]
  float* pbq4 = pb + 4096;                  // [srcQ|tgtQ|tgtK|tgtV] bias, Q scaled
  float* pb2  = pbq4 + 4096;                // [srcK|srcV] bias
  float* pbo  = pb2 + 2048;                 // bo_s + bo_t
  u16*   hbuf = (u16*)(ws + 73 * MiB);      // [513][16][1024]
  u16*   memb = (u16*)(ws + 90 * MiB);      // -> aot2 -> gx overlays
  u16*   aot2 = (u16*)(ws + 90 * MiB);      // [8192][2048] (ao_s|ao_t)
  u16*   gxb  = (u16*)(ws + 90 * MiB);      // [16*512][4096] bf16 (90..154)
  u16*   qx4  = (u16*)(ws + 122 * MiB);     // [8192][4096] (srcQ|tgtQ|tgtK|tgtV)
  u16*   kvs  = (u16*)(ws + 186 * MiB);     // [8192][2048] (srcK|srcV)
  u16*   wqt4 = (u16*)(ws + 218 * MiB);     // [4096][1024]
  u16*   wkv2 = (u16*)(ws + 226 * MiB);     // [2048][1024]
  u16*   wo2  = (u16*)(ws + 230 * MiB);     // [1024][2048]
  u16*   ffn1 = (u16*)(ws + 154 * MiB);     // [8192][4096] post-scan

  // sentinel-fill h rows 1..512 FIRST; scan polls via L2-bypass
  hipMemsetAsync(hbuf + 16384, 0xFF, (size_t)512 * 16384 * 2, stream);
  hipMemsetAsync(hbuf, 0, 32768, stream);   // h_0 = 0

  // --- conversions ---
  cvt_x_kernel<<<8192, 256, 0, stream>>>(xcb, x);
  cvt_bf16_kernel<<<8192, 256, 0, stream>>>(memb, mem, 2097152);
  const dim3 g1k(32, 32);
  convt_kernel<<<g1k, 256, 0, stream>>>(wqt4,                w_src_q, 1024, 1024, 0, 0.125f);
  convt_kernel<<<g1k, 256, 0, stream>>>(wqt4 + 1 * 1048576,  w_tgt_q, 1024, 1024, 0, 0.125f);
  convt_kernel<<<g1k, 256, 0, stream>>>(wqt4 + 2 * 1048576,  w_tgt_k, 1024, 1024, 0, 1.f);
  convt_kernel<<<g1k, 256, 0, stream>>>(wqt4 + 3 * 1048576,  w_tgt_v, 1024, 1024, 0, 1.f);
  convt_kernel<<<g1k, 256, 0, stream>>>(wkv2,                w_src_k, 1024, 1024, 0, 1.f);
  convt_kernel<<<g1k, 256, 0, stream>>>(wkv2 + 1048576,      w_src_v, 1024, 1024, 0, 1.f);
  convt_kernel<<<g1k, 256, 0, stream>>>(wo2,                 w_src_o, 2048, 1024, 0, 1.f);
  convt_kernel<<<g1k, 256, 0, stream>>>(wo2 + 1024,          w_tgt_o, 2048, 1024, 0, 1.f);
  convt_perm_kernel<<<dim3(32, 64, 4), 256, 0, stream>>>(wlp, lstm_w, 2048, 0);
  convt_perm_kernel<<<dim3(32, 32, 4), 256, 0, stream>>>(whp, lstm_w, 1024, 2048);
  convt_kernel<<<dim3(128, 32), 256, 0, stream>>>(w1t, w1, 1024, 4096, 0, 1.f);
  convt_kernel<<<dim3(32, 128), 256, 0, stream>>>(w2t, w2, 4096, 1024, 0, 1.f);
  pack_bias_kernel<<<16, 256, 0, stream>>>(pb, lstm_b);
  pack_bias4_kernel<<<16, 256, 0, stream>>>(pbq4, b_src_q, b_tgt_q, b_tgt_k, b_tgt_v, 0.125f);
  pack_bias2_kernel<<<8, 256, 0, stream>>>(pb2, b_src_k, b_src_v, 1.f);
  bias_sum_kernel<<<4, 256, 0, stream>>>(pbo, b_src_o, b_tgt_o);

  // --- projections: qx4 = x@[Wq_s|Wq_t|Wk_t|Wv_t], kvs = mem@[Wk_s|Wv_s] ---
  gemm_bt_kernel<1, 0, 0><<<dim3(32, 64), 256, 0, stream>>>(xcb, 2048, wqt4, pbq4, qx4, 4096, 1024);
  gemm_bt_kernel<1, 0, 0><<<dim3(16, 64), 256, 0, stream>>>(memb, 1024, wkv2, pb2, kvs, 2048, 1024);
  // --- attention (src writes aot2 cols 0-1023 [over dead memb], tgt cols 1024+)
  flash_kernel<0><<<dim3(8, 16, 16), 256, 0, stream>>>(qx4, kvs, kvs + 1024, src_bias, aot2, 4096, 2048, 2048);
  flash_kernel<1><<<dim3(8, 16, 16), 256, 0, stream>>>(qx4 + 1024, qx4 + 2048, qx4 + 3072, nullptr, aot2 + 1024, 4096, 4096, 2048);
  // --- c = [ao_s|ao_t] @ [Wo_s;Wo_t]^T + (bo_s+bo_t) -> xcb cols 1024+ ---
  gemm_bt_kernel<1, 0, 0><<<dim3(8, 64), 256, 0, stream>>>(aot2, 2048, wo2, pbo, xcb + 1024, 2048, 2048);
  // --- gx = [x|c] @ wlp^T + pb (bf16 out; overwrites dead aot2/qx4-head) ---
  gemm_bt_kernel<1, 0, 0><<<dim3(32, 64), 256, 0, stream>>>(xcb, 2048, wlp, pb, gxb, 4096, 2048);
  // --- LSTM scan: single persistent kernel, 32 WGs (all co-resident) ---
  lstm_scan_kernel<<<dim3(SCAN_NW), 256, 0, stream>>>(whp, gxb, hbuf);
  // --- FFN ---
  gemm_bt_kernel<1, 1, 0><<<dim3(32, 64), 256, 0, stream>>>(hbuf + 16384, 1024, w1t, b1f, ffn1, 4096, 1024);
  gemm_bt_kernel<0, 0, 2><<<dim3(8, 64), 256, 0, stream>>>(ffn1, 4096, w2t, b2f, (float*)d_out, 1024, 4096);
}